// Round 4
// baseline (261.880 us; speedup 1.0000x reference)
//
#include <hip/hip_runtime.h>

#define B_SZ 1024
#define F_SZ 32
#define D_SZ 128
#define FD   4096               // shorts per b-row of feature (bf16 buffer)
#define NPAIR 496               // F*(F-1)/2

typedef __bf16 bf16x8 __attribute__((ext_vector_type(8)));
typedef float floatx4 __attribute__((ext_vector_type(4)));
typedef unsigned short u16x8 __attribute__((ext_vector_type(8)));

__device__ __forceinline__ unsigned short f2bf(float f) {
  // round-to-nearest-even fp32 -> bf16 (no NaN inputs here)
  unsigned u = __float_as_uint(f);
  u += 0x7fffu + ((u >> 16) & 1u);
  return (unsigned short)(u >> 16);
}

__device__ __forceinline__ float bf2f(unsigned short h) {
  return __uint_as_float(((unsigned)h) << 16);
}

__device__ __forceinline__ void gload_lds16(const void* g, void* l) {
  // async 16B/lane global->LDS; LDS dest = wave-uniform base + lane*16
  __builtin_amdgcn_global_load_lds(
      (const __attribute__((address_space(1))) unsigned int*)g,
      (__attribute__((address_space(3))) unsigned int*)l,
      16, 0, 0);
}

// ---------------- fused prep: one dispatch, 3 sections by blockIdx ----------
// [0, 992):        Z -> sigmoid/stretch/clip -> bf16, transposed [e][d],
//                  XOR-swizzled in 8-short groups (group g stored at g^(e&7))
//                  so main can stage LINEAR global_load_lds + conflict-free
//                  ds_read_b128. 2 blocks per pair (d-halves).
// [992, 2016):     feature fp32 -> bf16 (used by BOTH stage-1 and epilogue).
// [2016, 2272):    zero the output (diagonal + lower triangle stay 0).
__global__ __launch_bounds__(256)
void prep_kernel(const float* __restrict__ feat, const float* __restrict__ mat,
                 unsigned short* __restrict__ featB,
                 unsigned short* __restrict__ ZT, float* __restrict__ out) {
  const int bid = blockIdx.x, t = threadIdx.x;
  __shared__ unsigned short tr[128 * 72];   // [e][d-half], 144B rows (16B-aligned)

  if (bid < 2 * NPAIR) {
    const int pid = bid >> 1, h = bid & 1, d0 = h * 64;
    int p = pid, i = 0;
    while (p >= F_SZ - 1 - i) { p -= F_SZ - 1 - i; ++i; }
    const int j = i + 1 + p;
    const float* zp = mat + (((size_t)i * F_SZ + j) * (size_t)(D_SZ * D_SZ));
    #pragma unroll
    for (int it = 0; it < 8; ++it) {
      int idx4 = it * 256 + t;               // 2048 float4 groups (64 d x 32 e4)
      int dl = idx4 >> 5, e4 = (idx4 & 31) * 4;
      const float4 v = *(const float4*)(zp + (size_t)(d0 + dl) * D_SZ + e4);
      float zs[4] = {v.x, v.y, v.z, v.w};
      #pragma unroll
      for (int c = 0; c < 4; ++c) {
        float s = 1.0f / (1.0f + __expf(-zs[c]));
        float z = fminf(1.0f, fmaxf(0.0f, fmaf(s, 1.2f, -0.1f)));
        tr[(e4 + c) * 72 + dl] = f2bf(z);    // transposed store
      }
    }
    __syncthreads();
    #pragma unroll
    for (int it = 0; it < 4; ++it) {
      int G = it * 256 + t;                  // 1024: e(128) x out-group gl(8)
      int e = G >> 3, gl = G & 7;
      int gs = gl ^ (e & 7);                 // source d-local 8-short group
      u16x8 v = *(const u16x8*)&tr[e * 72 + gs * 8];
      *(u16x8*)&ZT[(size_t)pid * (D_SZ * D_SZ) + e * 128 + d0 + gl * 8] = v;
    }
  } else if (bid < 2 * NPAIR + 1024) {
    int idx = (bid - 2 * NPAIR) * 256 + t;   // 262144 threads x 16 floats
    const float4* f4 = (const float4*)feat + (size_t)idx * 4;
    #pragma unroll
    for (int q = 0; q < 2; ++q) {
      float4 a = f4[q * 2], b = f4[q * 2 + 1];
      float vs[8] = {a.x, a.y, a.z, a.w, b.x, b.y, b.z, b.w};
      u16x8 hi;
      #pragma unroll
      for (int c = 0; c < 8; ++c) hi[c] = f2bf(vs[c]);
      *(u16x8*)&featB[(size_t)idx * 16 + q * 8] = hi;
    }
  } else {
    int idx = (bid - (2 * NPAIR + 1024)) * 256 + t;  // 65536 threads x 16 f32
    float4* o4 = (float4*)out + (size_t)idx * 4;
    float4 z = {0.f, 0.f, 0.f, 0.f};
    o4[0] = z; o4[1] = z; o4[2] = z; o4[3] = z;
  }
}

// ---------------- main: 1984 blocks = 496 pairs x 4 splits; 4 waves ----------
// W-orientation: acc[m][n] = MFMA(A = Z^T e-rows from LDS, B = f_i b-cols from
// global bf16) -> C[row=e, col=b=lane&15]. Reduction axis (e) is LANE-LOCAL:
// epilogue = 8 ushort4 bf16 f_j loads + 32 FMAs + 2 shuffles per 16-row group.
// Z frags re-read from conflict-free swizzled LDS per pass (no reg pin ->
// <=128 regs -> 4 waves/SIMD). XCD-chunked remap co-locates the 4 same-pair
// splits and consecutive pairs on one XCD's L2. ONE barrier per block.
__global__ __launch_bounds__(256, 4)
void interaction_pair_kernel(const unsigned short* __restrict__ featB,
                             const unsigned short* __restrict__ ZT,
                             float* __restrict__ out) {
  __shared__ unsigned short sZ[128 * 128];   // 32KB swizzled [e][d']

  const int t    = threadIdx.x;
  const int w    = t >> 6;
  const int lane = t & 63;
  const int l15  = lane & 15;
  const int quad = lane >> 4;
  const int swz  = (l15 & 7) << 4;           // byte-level 16B-group XOR swizzle

  // HW dispatches block n -> XCD n%8; remap so each XCD owns a CONTIGUOUS
  // work range (1984 = 8 * 248): same-pair splits + same-i pairs share L2.
  const int bid  = blockIdx.x;
  const int work = (bid & 7) * 248 + (bid >> 3);
  const int pid   = work >> 2;
  const int split = work & 3;
  int p = pid, i = 0;
  while (p >= F_SZ - 1 - i) { p -= F_SZ - 1 - i; ++i; }
  const int j = i + 1 + p;

  // ---- stage sZ: 32KB linear async copy (content pre-swizzled by prep) ----
  {
    const char* src = (const char*)(ZT + (size_t)pid * (D_SZ * D_SZ));
    #pragma unroll
    for (int it = 0; it < 8; ++it) {
      int off = it * 4096 + w * 1024;        // wave-uniform LDS offset
      gload_lds16(src + off + lane * 16, (char*)sZ + off);
    }
  }
  __syncthreads();   // the ONLY barrier

  #pragma unroll 1
  for (int pass = 0; pass < 2; ++pass) {
    const int rbase = split * 256 + pass * 128 + w * 32;  // wave's 32 b-rows

    floatx4 acc[8][2];
    #pragma unroll
    for (int m = 0; m < 8; ++m) {
      acc[m][0] = (floatx4){0.f, 0.f, 0.f, 0.f};
      acc[m][1] = (floatx4){0.f, 0.f, 0.f, 0.f};
    }

    // stage 1: W[e=128, b=32] for this wave; Z frags shared by both 16-b cols
    const unsigned short* bp0 = featB + (size_t)(rbase + l15) * FD + i * D_SZ + quad * 8;
    const unsigned short* bp1 = bp0 + (size_t)16 * FD;
    #pragma unroll
    for (int k0 = 0; k0 < 4; ++k0) {
      bf16x8 b0 = *(const bf16x8*)(bp0 + k0 * 32);   // f_i[b,   d-chunk]
      bf16x8 b1 = *(const bf16x8*)(bp1 + k0 * 32);   // f_i[b+16,d-chunk]
      #pragma unroll
      for (int m = 0; m < 8; ++m) {
        bf16x8 za = *(const bf16x8*)((const char*)sZ + (m * 16 + l15) * 256 +
                                     ((k0 * 64 + quad * 16) ^ swz));
        acc[m][0] = __builtin_amdgcn_mfma_f32_16x16x32_bf16(za, b0, acc[m][0], 0, 0, 0);
        acc[m][1] = __builtin_amdgcn_mfma_f32_16x16x32_bf16(za, b1, acc[m][1], 0, 0, 0);
      }
    }

    // epilogue: out[b] = sum_e W[e,b] * f_j[b,e]; e is lane-local.
    // C-layout: col(b) = l15, row(e within m-tile) = quad*4 + reg
    #pragma unroll
    for (int n = 0; n < 2; ++n) {
      const int row = rbase + n * 16 + l15;
      const unsigned short* fj = featB + (size_t)row * FD + j * D_SZ + quad * 4;
      float pl = 0.f;
      #pragma unroll
      for (int m = 0; m < 8; ++m) {
        const ushort4 hv = *(const ushort4*)(fj + m * 16);   // bf16 f_j, 8B
        floatx4 c = acc[m][n];
        pl += c[0] * bf2f(hv.x) + c[1] * bf2f(hv.y)
            + c[2] * bf2f(hv.z) + c[3] * bf2f(hv.w);
      }
      pl += __shfl_xor(pl, 16, 64);          // reduce over quad (e-chunks)
      pl += __shfl_xor(pl, 32, 64);
      if (quad == 0)
        out[(size_t)row * (F_SZ * F_SZ) + (size_t)i * F_SZ + j] = pl;
    }
  }
}

extern "C" void kernel_launch(void* const* d_in, const int* in_sizes, int n_in,
                              void* d_out, int out_size, void* d_ws, size_t ws_size,
                              hipStream_t stream) {
  const float* feat = (const float*)d_in[0];   // [B, F, D] fp32
  const float* mat  = (const float*)d_in[1];   // [F, F, D, D] fp32
  float* out = (float*)d_out;                  // [B, F, F] fp32

  unsigned short* featB = (unsigned short*)d_ws;                   // 8.4MB bf16
  unsigned short* ZT    = featB + (size_t)B_SZ * F_SZ * D_SZ;      // 16.3MB bf16

  const int prep_grid = 2 * NPAIR + 1024 + 256;   // 2272
  prep_kernel<<<dim3(prep_grid), dim3(256), 0, stream>>>(feat, mat, featB, ZT, out);
  interaction_pair_kernel<<<dim3(NPAIR * 4), dim3(256), 0, stream>>>(featB, ZT, out);
}

// Round 5
// 155.004 us; speedup vs baseline: 1.6895x; 1.6895x over previous
//
#include <hip/hip_runtime.h>

#define B_SZ 1024
#define F_SZ 32
#define D_SZ 128
#define FD   4096               // shorts per b-row of feature (bf16 buffer)
#define NPAIR 496               // F*(F-1)/2

typedef __bf16 bf16x8 __attribute__((ext_vector_type(8)));
typedef float floatx4 __attribute__((ext_vector_type(4)));
typedef unsigned short u16x8 __attribute__((ext_vector_type(8)));

__device__ __forceinline__ unsigned short f2bf(float f) {
  // round-to-nearest-even fp32 -> bf16 (no NaN inputs here)
  unsigned u = __float_as_uint(f);
  u += 0x7fffu + ((u >> 16) & 1u);
  return (unsigned short)(u >> 16);
}

__device__ __forceinline__ float bf2f(unsigned short h) {
  return __uint_as_float(((unsigned)h) << 16);
}

__device__ __forceinline__ void gload_lds16(const void* g, void* l) {
  // async 16B/lane global->LDS; LDS dest = wave-uniform base + lane*16
  __builtin_amdgcn_global_load_lds(
      (const __attribute__((address_space(1))) unsigned int*)g,
      (__attribute__((address_space(3))) unsigned int*)l,
      16, 0, 0);
}

// ---------------- fused prep: one dispatch, 3 sections by blockIdx ----------
// [0, 992):        Z -> sigmoid/stretch/clip -> bf16, transposed [e][d],
//                  XOR-swizzled in 8-short groups (group g stored at g^(e&7))
//                  so main can stage LINEAR global_load_lds + conflict-free
//                  ds_read_b128. 2 blocks per pair (d-halves).
// [992, 2016):     feature fp32 -> bf16 (used by BOTH stage-1 and epilogue).
// [2016, 2272):    zero the output (diagonal + lower triangle stay 0).
__global__ __launch_bounds__(256)
void prep_kernel(const float* __restrict__ feat, const float* __restrict__ mat,
                 unsigned short* __restrict__ featB,
                 unsigned short* __restrict__ ZT, float* __restrict__ out) {
  const int bid = blockIdx.x, t = threadIdx.x;
  __shared__ unsigned short tr[128 * 72];   // [e][d-half], 144B rows (16B-aligned)

  if (bid < 2 * NPAIR) {
    const int pid = bid >> 1, h = bid & 1, d0 = h * 64;
    int p = pid, i = 0;
    while (p >= F_SZ - 1 - i) { p -= F_SZ - 1 - i; ++i; }
    const int j = i + 1 + p;
    const float* zp = mat + (((size_t)i * F_SZ + j) * (size_t)(D_SZ * D_SZ));
    #pragma unroll
    for (int it = 0; it < 8; ++it) {
      int idx4 = it * 256 + t;               // 2048 float4 groups (64 d x 32 e4)
      int dl = idx4 >> 5, e4 = (idx4 & 31) * 4;
      const float4 v = *(const float4*)(zp + (size_t)(d0 + dl) * D_SZ + e4);
      float zs[4] = {v.x, v.y, v.z, v.w};
      #pragma unroll
      for (int c = 0; c < 4; ++c) {
        float s = 1.0f / (1.0f + __expf(-zs[c]));
        float z = fminf(1.0f, fmaxf(0.0f, fmaf(s, 1.2f, -0.1f)));
        tr[(e4 + c) * 72 + dl] = f2bf(z);    // transposed store
      }
    }
    __syncthreads();
    #pragma unroll
    for (int it = 0; it < 4; ++it) {
      int G = it * 256 + t;                  // 1024: e(128) x out-group gl(8)
      int e = G >> 3, gl = G & 7;
      int gs = gl ^ (e & 7);                 // source d-local 8-short group
      u16x8 v = *(const u16x8*)&tr[e * 72 + gs * 8];
      *(u16x8*)&ZT[(size_t)pid * (D_SZ * D_SZ) + e * 128 + d0 + gl * 8] = v;
    }
  } else if (bid < 2 * NPAIR + 1024) {
    int idx = (bid - 2 * NPAIR) * 256 + t;   // 262144 threads x 16 floats
    const float4* f4 = (const float4*)feat + (size_t)idx * 4;
    #pragma unroll
    for (int q = 0; q < 2; ++q) {
      float4 a = f4[q * 2], b = f4[q * 2 + 1];
      float vs[8] = {a.x, a.y, a.z, a.w, b.x, b.y, b.z, b.w};
      u16x8 hi;
      #pragma unroll
      for (int c = 0; c < 8; ++c) hi[c] = f2bf(vs[c]);
      *(u16x8*)&featB[(size_t)idx * 16 + q * 8] = hi;
    }
  } else {
    int idx = (bid - (2 * NPAIR + 1024)) * 256 + t;  // 65536 threads x 16 f32
    float4* o4 = (float4*)out + (size_t)idx * 4;
    float4 z = {0.f, 0.f, 0.f, 0.f};
    o4[0] = z; o4[1] = z; o4[2] = z; o4[3] = z;
  }
}

// ---------------- main: 1984 blocks = 496 pairs x 4 splits; 4 waves ----------
// W-orientation: acc[m][n] = MFMA(A = Z^T e-rows from LDS, B = f_i b-cols from
// global bf16) -> C[row=e, col=b=lane&15]. Reduction axis (e) is LANE-LOCAL:
// epilogue = 8 ushort4 bf16 f_j loads + 32 FMAs + 2 shuffles per 16-row group.
// Z frags re-read from conflict-free swizzled LDS (no reg pin). XCD-chunked
// remap co-locates same-pair splits + same-i pairs on one XCD's L2.
// __launch_bounds__(256,2): 64 acc (AGPR) + ~112 VGPR needs the 256-reg
// budget — (256,4) in round 4 capped at 128 and spilled acc to scratch
// (WRITE_SIZE 9->267MB, 3x slower). DO NOT raise the occupancy bound.
__global__ __launch_bounds__(256, 2)
void interaction_pair_kernel(const unsigned short* __restrict__ featB,
                             const unsigned short* __restrict__ ZT,
                             float* __restrict__ out) {
  __shared__ unsigned short sZ[128 * 128];   // 32KB swizzled [e][d']

  const int t    = threadIdx.x;
  const int w    = t >> 6;
  const int lane = t & 63;
  const int l15  = lane & 15;
  const int quad = lane >> 4;
  const int swz  = (l15 & 7) << 4;           // byte-level 16B-group XOR swizzle

  // HW dispatches block n -> XCD n%8; remap so each XCD owns a CONTIGUOUS
  // work range (1984 = 8 * 248): same-pair splits + same-i pairs share L2.
  const int bid  = blockIdx.x;
  const int work = (bid & 7) * 248 + (bid >> 3);
  const int pid   = work >> 2;
  const int split = work & 3;
  int p = pid, i = 0;
  while (p >= F_SZ - 1 - i) { p -= F_SZ - 1 - i; ++i; }
  const int j = i + 1 + p;

  // ---- stage sZ: 32KB linear async copy (content pre-swizzled by prep) ----
  {
    const char* src = (const char*)(ZT + (size_t)pid * (D_SZ * D_SZ));
    #pragma unroll
    for (int it = 0; it < 8; ++it) {
      int off = it * 4096 + w * 1024;        // wave-uniform LDS offset
      gload_lds16(src + off + lane * 16, (char*)sZ + off);
    }
  }
  __syncthreads();   // the ONLY barrier

  #pragma unroll 1
  for (int pass = 0; pass < 2; ++pass) {
    const int rbase = split * 256 + pass * 128 + w * 32;  // wave's 32 b-rows

    floatx4 acc[8][2];
    #pragma unroll
    for (int m = 0; m < 8; ++m) {
      acc[m][0] = (floatx4){0.f, 0.f, 0.f, 0.f};
      acc[m][1] = (floatx4){0.f, 0.f, 0.f, 0.f};
    }

    // stage 1: W[e=128, b=32] for this wave; Z frags shared by both 16-b cols
    const unsigned short* bp0 = featB + (size_t)(rbase + l15) * FD + i * D_SZ + quad * 8;
    const unsigned short* bp1 = bp0 + (size_t)16 * FD;
    #pragma unroll
    for (int k0 = 0; k0 < 4; ++k0) {
      bf16x8 b0 = *(const bf16x8*)(bp0 + k0 * 32);   // f_i[b,   d-chunk]
      bf16x8 b1 = *(const bf16x8*)(bp1 + k0 * 32);   // f_i[b+16,d-chunk]
      #pragma unroll
      for (int m = 0; m < 8; ++m) {
        bf16x8 za = *(const bf16x8*)((const char*)sZ + (m * 16 + l15) * 256 +
                                     ((k0 * 64 + quad * 16) ^ swz));
        acc[m][0] = __builtin_amdgcn_mfma_f32_16x16x32_bf16(za, b0, acc[m][0], 0, 0, 0);
        acc[m][1] = __builtin_amdgcn_mfma_f32_16x16x32_bf16(za, b1, acc[m][1], 0, 0, 0);
      }
    }

    // epilogue: out[b] = sum_e W[e,b] * f_j[b,e]; e is lane-local.
    // C-layout: col(b) = l15, row(e within m-tile) = quad*4 + reg
    #pragma unroll
    for (int n = 0; n < 2; ++n) {
      const int row = rbase + n * 16 + l15;
      const unsigned short* fj = featB + (size_t)row * FD + j * D_SZ + quad * 4;
      float pl = 0.f;
      #pragma unroll
      for (int m = 0; m < 8; ++m) {
        const ushort4 hv = *(const ushort4*)(fj + m * 16);   // bf16 f_j, 8B
        floatx4 c = acc[m][n];
        pl += c[0] * bf2f(hv.x) + c[1] * bf2f(hv.y)
            + c[2] * bf2f(hv.z) + c[3] * bf2f(hv.w);
      }
      pl += __shfl_xor(pl, 16, 64);          // reduce over quad (e-chunks)
      pl += __shfl_xor(pl, 32, 64);
      if (quad == 0)
        out[(size_t)row * (F_SZ * F_SZ) + (size_t)i * F_SZ + j] = pl;
    }
  }
}

extern "C" void kernel_launch(void* const* d_in, const int* in_sizes, int n_in,
                              void* d_out, int out_size, void* d_ws, size_t ws_size,
                              hipStream_t stream) {
  const float* feat = (const float*)d_in[0];   // [B, F, D] fp32
  const float* mat  = (const float*)d_in[1];   // [F, F, D, D] fp32
  float* out = (float*)d_out;                  // [B, F, F] fp32

  unsigned short* featB = (unsigned short*)d_ws;                   // 8.4MB bf16
  unsigned short* ZT    = featB + (size_t)B_SZ * F_SZ * D_SZ;      // 16.3MB bf16

  const int prep_grid = 2 * NPAIR + 1024 + 256;   // 2272
  prep_kernel<<<dim3(prep_grid), dim3(256), 0, stream>>>(feat, mat, featB, ZT, out);
  interaction_pair_kernel<<<dim3(NPAIR * 4), dim3(256), 0, stream>>>(featB, ZT, out);
}

// Round 6
// 153.506 us; speedup vs baseline: 1.7060x; 1.0098x over previous
//
#include <hip/hip_runtime.h>

#define B_SZ 1024
#define F_SZ 32
#define D_SZ 128
#define FD   4096               // shorts per b-row of feature (bf16 buffer)
#define NPAIR 496               // F*(F-1)/2

typedef __bf16 bf16x8 __attribute__((ext_vector_type(8)));
typedef float floatx4 __attribute__((ext_vector_type(4)));
typedef unsigned short u16x8 __attribute__((ext_vector_type(8)));

__device__ __forceinline__ unsigned short f2bf(float f) {
  // round-to-nearest-even fp32 -> bf16 (no NaN inputs here)
  unsigned u = __float_as_uint(f);
  u += 0x7fffu + ((u >> 16) & 1u);
  return (unsigned short)(u >> 16);
}

__device__ __forceinline__ float bf2f(unsigned short h) {
  return __uint_as_float(((unsigned)h) << 16);
}

__device__ __forceinline__ void gload_lds16(const void* g, void* l) {
  // async 16B/lane global->LDS; LDS dest = wave-uniform base + lane*16
  __builtin_amdgcn_global_load_lds(
      (const __attribute__((address_space(1))) unsigned int*)g,
      (__attribute__((address_space(3))) unsigned int*)l,
      16, 0, 0);
}

// ---------------- fused prep: one dispatch, 3 sections by blockIdx ----------
// [0, 992):        Z -> sigmoid/stretch/clip -> bf16, transposed [e][d],
//                  XOR-swizzled in 8-short groups (group g stored at g^(e&7))
//                  so main can stage LINEAR global_load_lds + conflict-free
//                  ds_read_b128. 2 blocks per pair (d-halves).
// [992, 2016):     feature fp32 -> bf16 (used by BOTH stage-1 and epilogue).
// [2016, 2272):    zero the output (diagonal + lower triangle stay 0).
__global__ __launch_bounds__(256)
void prep_kernel(const float* __restrict__ feat, const float* __restrict__ mat,
                 unsigned short* __restrict__ featB,
                 unsigned short* __restrict__ ZT, float* __restrict__ out) {
  const int bid = blockIdx.x, t = threadIdx.x;
  __shared__ unsigned short tr[128 * 72];   // [e][d-half], 144B rows (16B-aligned)

  if (bid < 2 * NPAIR) {
    const int pid = bid >> 1, h = bid & 1, d0 = h * 64;
    int p = pid, i = 0;
    while (p >= F_SZ - 1 - i) { p -= F_SZ - 1 - i; ++i; }
    const int j = i + 1 + p;
    const float* zp = mat + (((size_t)i * F_SZ + j) * (size_t)(D_SZ * D_SZ));
    #pragma unroll
    for (int it = 0; it < 8; ++it) {
      int idx4 = it * 256 + t;               // 2048 float4 groups (64 d x 32 e4)
      int dl = idx4 >> 5, e4 = (idx4 & 31) * 4;
      const float4 v = *(const float4*)(zp + (size_t)(d0 + dl) * D_SZ + e4);
      float zs[4] = {v.x, v.y, v.z, v.w};
      #pragma unroll
      for (int c = 0; c < 4; ++c) {
        float s = 1.0f / (1.0f + __expf(-zs[c]));
        float z = fminf(1.0f, fmaxf(0.0f, fmaf(s, 1.2f, -0.1f)));
        tr[(e4 + c) * 72 + dl] = f2bf(z);    // transposed store
      }
    }
    __syncthreads();
    #pragma unroll
    for (int it = 0; it < 4; ++it) {
      int G = it * 256 + t;                  // 1024: e(128) x out-group gl(8)
      int e = G >> 3, gl = G & 7;
      int gs = gl ^ (e & 7);                 // source d-local 8-short group
      u16x8 v = *(const u16x8*)&tr[e * 72 + gs * 8];
      *(u16x8*)&ZT[(size_t)pid * (D_SZ * D_SZ) + e * 128 + d0 + gl * 8] = v;
    }
  } else if (bid < 2 * NPAIR + 1024) {
    int idx = (bid - 2 * NPAIR) * 256 + t;   // 262144 threads x 16 floats
    const float4* f4 = (const float4*)feat + (size_t)idx * 4;
    #pragma unroll
    for (int q = 0; q < 2; ++q) {
      float4 a = f4[q * 2], b = f4[q * 2 + 1];
      float vs[8] = {a.x, a.y, a.z, a.w, b.x, b.y, b.z, b.w};
      u16x8 hi;
      #pragma unroll
      for (int c = 0; c < 8; ++c) hi[c] = f2bf(vs[c]);
      *(u16x8*)&featB[(size_t)idx * 16 + q * 8] = hi;
    }
  } else {
    int idx = (bid - (2 * NPAIR + 1024)) * 256 + t;  // 65536 threads x 16 f32
    float4* o4 = (float4*)out + (size_t)idx * 4;
    float4 z = {0.f, 0.f, 0.f, 0.f};
    o4[0] = z; o4[1] = z; o4[2] = z; o4[3] = z;
  }
}

// one fully-unrolled pass: MFMA (A = Z^T from swizzled LDS, B = f_i regs) then
// lane-local e-reduction epilogue against prefetched bf16 f_j regs.
#define DO_PASS(FI, FJ, RB)                                                    \
  {                                                                            \
    floatx4 acc[8][2];                                                         \
    _Pragma("unroll") for (int m = 0; m < 8; ++m) {                            \
      acc[m][0] = (floatx4){0.f, 0.f, 0.f, 0.f};                               \
      acc[m][1] = (floatx4){0.f, 0.f, 0.f, 0.f};                               \
    }                                                                          \
    _Pragma("unroll") for (int k0 = 0; k0 < 4; ++k0) {                         \
      _Pragma("unroll") for (int m = 0; m < 8; ++m) {                          \
        bf16x8 za = *(const bf16x8*)((const char*)sZ + (m * 16 + l15) * 256 +  \
                                     ((k0 * 64 + quad * 16) ^ swz));           \
        acc[m][0] = __builtin_amdgcn_mfma_f32_16x16x32_bf16(za, FI[k0],        \
                                                            acc[m][0], 0, 0, 0);\
        acc[m][1] = __builtin_amdgcn_mfma_f32_16x16x32_bf16(za, FI[4 + k0],    \
                                                            acc[m][1], 0, 0, 0);\
      }                                                                        \
    }                                                                          \
    _Pragma("unroll") for (int n = 0; n < 2; ++n) {                            \
      float pl = 0.f;                                                          \
      _Pragma("unroll") for (int m = 0; m < 8; ++m) {                          \
        const ushort4 hv = FJ[n * 8 + m];                                      \
        const floatx4 c = acc[m][n];                                           \
        pl += c[0] * bf2f(hv.x) + c[1] * bf2f(hv.y)                            \
            + c[2] * bf2f(hv.z) + c[3] * bf2f(hv.w);                           \
      }                                                                        \
      pl += __shfl_xor(pl, 16, 64);                                            \
      pl += __shfl_xor(pl, 32, 64);                                            \
      if (quad == 0)                                                           \
        out[(size_t)(RB + n * 16 + l15) * (F_SZ * F_SZ) +                      \
            (size_t)i * F_SZ + j] = pl;                                        \
    }                                                                          \
  }

// ---------------- main: 1984 blocks = 496 pairs x 4 splits; 4 waves ----------
// Software-pipelined: pass-0's f_i/f_j global loads are issued BEFORE the sZ
// DMA stage (one shared HBM round-trip before the barrier); pass-1's loads are
// issued at the top of pass-0 compute and hide under 64 MFMAs + epilogue.
// Natural block order (NO XCD remap — R5's remap was a regression suspect).
// __launch_bounds__(256,2): ~225 regs/thread; (256,4) spilled acc in R4
// (WRITE_SIZE 9->267MB). DO NOT raise the occupancy bound.
__global__ __launch_bounds__(256, 2)
void interaction_pair_kernel(const unsigned short* __restrict__ featB,
                             const unsigned short* __restrict__ ZT,
                             float* __restrict__ out) {
  __shared__ unsigned short sZ[128 * 128];   // 32KB swizzled [e][d']

  const int t    = threadIdx.x;
  const int w    = t >> 6;
  const int lane = t & 63;
  const int l15  = lane & 15;
  const int quad = lane >> 4;
  const int swz  = (l15 & 7) << 4;           // byte-level 16B-group XOR swizzle

  const int bid   = blockIdx.x;
  const int pid   = bid >> 2;
  const int split = bid & 3;
  int p = pid, i = 0;
  while (p >= F_SZ - 1 - i) { p -= F_SZ - 1 - i; ++i; }
  const int j = i + 1 + p;

  const int rb0 = split * 256 + w * 32;      // wave's pass-0 rows
  const int rb1 = rb0 + 128;                 // wave's pass-1 rows

  // ---- prefetch ALL pass-0 operands (independent of the LDS stage) ----
  bf16x8 fiA[8];   // f_i frags: [g*... ] g=0: rows rb0+l15, g=1: rows rb0+16+l15
  ushort4 fjA[16]; // f_j bf16: [n*8+m]
  {
    const unsigned short* bp = featB + (size_t)(rb0 + l15) * FD + i * D_SZ + quad * 8;
    #pragma unroll
    for (int k0 = 0; k0 < 4; ++k0) {
      fiA[k0]     = *(const bf16x8*)(bp + k0 * 32);
      fiA[4 + k0] = *(const bf16x8*)(bp + (size_t)16 * FD + k0 * 32);
    }
    #pragma unroll
    for (int n = 0; n < 2; ++n) {
      const unsigned short* fj =
          featB + (size_t)(rb0 + n * 16 + l15) * FD + j * D_SZ + quad * 4;
      #pragma unroll
      for (int m = 0; m < 8; ++m) fjA[n * 8 + m] = *(const ushort4*)(fj + m * 16);
    }
  }

  // ---- stage sZ: 32KB linear async DMA (overlaps the prefetches above) ----
  {
    const char* src = (const char*)(ZT + (size_t)pid * (D_SZ * D_SZ));
    #pragma unroll
    for (int it = 0; it < 8; ++it) {
      int off = it * 4096 + w * 1024;        // wave-uniform LDS offset
      gload_lds16(src + off + lane * 16, (char*)sZ + off);
    }
  }
  __syncthreads();   // the ONLY barrier (drains vmcnt: DMA + prefetches done)

  // ---- pass 0: issue pass-1 prefetch first (hides under compute) ----
  bf16x8 fiB[8];
  ushort4 fjB[16];
  {
    const unsigned short* bp = featB + (size_t)(rb1 + l15) * FD + i * D_SZ + quad * 8;
    #pragma unroll
    for (int k0 = 0; k0 < 4; ++k0) {
      fiB[k0]     = *(const bf16x8*)(bp + k0 * 32);
      fiB[4 + k0] = *(const bf16x8*)(bp + (size_t)16 * FD + k0 * 32);
    }
    #pragma unroll
    for (int n = 0; n < 2; ++n) {
      const unsigned short* fj =
          featB + (size_t)(rb1 + n * 16 + l15) * FD + j * D_SZ + quad * 4;
      #pragma unroll
      for (int m = 0; m < 8; ++m) fjB[n * 8 + m] = *(const ushort4*)(fj + m * 16);
    }
  }

  DO_PASS(fiA, fjA, rb0);

  // ---- pass 1 ----
  DO_PASS(fiB, fjB, rb1);
}

extern "C" void kernel_launch(void* const* d_in, const int* in_sizes, int n_in,
                              void* d_out, int out_size, void* d_ws, size_t ws_size,
                              hipStream_t stream) {
  const float* feat = (const float*)d_in[0];   // [B, F, D] fp32
  const float* mat  = (const float*)d_in[1];   // [F, F, D, D] fp32
  float* out = (float*)d_out;                  // [B, F, F] fp32

  unsigned short* featB = (unsigned short*)d_ws;                   // 8.4MB bf16
  unsigned short* ZT    = featB + (size_t)B_SZ * F_SZ * D_SZ;      // 16.3MB bf16

  const int prep_grid = 2 * NPAIR + 1024 + 256;   // 2272
  prep_kernel<<<dim3(prep_grid), dim3(256), 0, stream>>>(feat, mat, featB, ZT, out);
  interaction_pair_kernel<<<dim3(NPAIR * 4), dim3(256), 0, stream>>>(featB, ZT, out);
}

// Round 7
// 152.696 us; speedup vs baseline: 1.7150x; 1.0053x over previous
//
#include <hip/hip_runtime.h>

#define B_SZ 1024
#define F_SZ 32
#define D_SZ 128
#define FD   4096               // floats per b-row of feature (fp32 input)
#define NPAIR 496               // F*(F-1)/2

typedef __bf16 bf16x8 __attribute__((ext_vector_type(8)));
typedef float floatx4 __attribute__((ext_vector_type(4)));
typedef unsigned short u16x8 __attribute__((ext_vector_type(8)));

__device__ __forceinline__ unsigned short f2bf(float f) {
  // round-to-nearest-even fp32 -> bf16 (no NaN inputs here)
  unsigned u = __float_as_uint(f);
  u += 0x7fffu + ((u >> 16) & 1u);
  return (unsigned short)(u >> 16);
}

// ---------------- single fused kernel: 1984 blocks = 496 pairs x 4 splits ----
// Per block: (1) zero a disjoint slice of the output triangle (blocks < 1024),
// (2) inline Z: coalesced fp32 read -> sigmoid/stretch/clip -> bf16 -> in-LDS
//     transpose -> XOR-swizzled sZT[e][d] (all phases <=2-way bank aliasing),
// (3) 2 passes of 128 b-rows: coalesced-stage f_i (fp32->bf16, swizzled sA),
//     R1-verified MFMA core (A=f_i rows, B=Z^T, C: col=e=lane&15,
//     row=b=quad*4+reg), 16-lane-coalesced fp32 f_j epilogue + butterfly.
// ONE dispatch total: no prep kernel, no memset. Zero-writes hit only j<=i
// slots, pair-writes only j>i slots -> disjoint, race-free, order-free.
// __launch_bounds__(256,2): acc(64 AGPR)+~120 VGPR needs the 256 budget;
// (256,4) spilled in R4 (WRITE_SIZE 9->267MB). DO NOT raise.
__global__ __launch_bounds__(256, 2)
void interaction_fused_kernel(const float* __restrict__ feat,
                              const float* __restrict__ mat,
                              float* __restrict__ out) {
  __shared__ unsigned short sZT[128 * 128];  // 32KB persistent: Z^T [e][d-swz]
  __shared__ unsigned short sS[128 * 128];   // 32KB scratch: Z-tmp, then sA

  const int t    = threadIdx.x;
  const int w    = t >> 6;
  const int lane = t & 63;
  const int l15  = lane & 15;
  const int quad = lane >> 4;

  const int bid   = blockIdx.x;
  const int pid   = bid >> 2;
  const int split = bid & 3;
  int p = pid, i = 0;
  while (p >= F_SZ - 1 - i) { p -= F_SZ - 1 - i; ++i; }
  const int j = i + 1 + p;

  // ---- (1) zero diag + lower triangle of batch b = bid (blocks < 1024) ----
  // addresses j<=i are never touched by any pair-writer -> no ordering needed
  if (bid < B_SZ) {
    const int ii = t >> 3, s = t & 7;
    float* ob = out + (size_t)bid * (F_SZ * F_SZ) + ii * F_SZ;
    #pragma unroll
    for (int c = 0; c < 4; ++c) {
      int jj = s * 4 + c;
      if (jj <= ii) ob[jj] = 0.f;
    }
  }

  // ---- (2a) Z: coalesced fp32 read, gate transform, bf16, linear [d][e] ----
  {
    const float* zp = mat + (((size_t)i * F_SZ + j) * (size_t)(D_SZ * D_SZ));
    #pragma unroll
    for (int it = 0; it < 16; ++it) {
      int idx4 = it * 256 + t;               // 4096 float4 (e fastest)
      int d = idx4 >> 5, e4 = (idx4 & 31) * 4;
      const float4 v = *(const float4*)(zp + (size_t)d * D_SZ + e4);
      float zs[4] = {v.x, v.y, v.z, v.w};
      ushort4 h;
      unsigned short* hp = &h.x;
      #pragma unroll
      for (int c = 0; c < 4; ++c) {
        float s = 1.0f / (1.0f + __expf(-zs[c]));
        hp[c] = f2bf(fminf(1.0f, fmaxf(0.0f, fmaf(s, 1.2f, -0.1f))));
      }
      *(ushort4*)&sS[d * D_SZ + e4] = h;     // 8B writes, 2-way aliasing: free
    }
  }
  __syncthreads();

  // ---- (2b) transpose sS[d][e] -> sZT[e][d], 16B-group XOR swizzle ----
  // read: u16 at bank (e>>1)%32, lanes have consecutive e -> 2-way: free.
  // write: b128, 8-lane groups cover bank-quads 0..7 exactly once: free.
  {
    #pragma unroll
    for (int it = 0; it < 8; ++it) {
      int u = it * 256 + t;                  // 2048 units: e(128) x g(16)
      int e = u & 127, g = u >> 7;
      u16x8 pk;
      #pragma unroll
      for (int r = 0; r < 8; ++r) pk[r] = sS[(g * 8 + r) * D_SZ + e];
      *(u16x8*)&sZT[e * D_SZ + (g ^ (e & 7)) * 8] = pk;
    }
  }
  __syncthreads();

  #pragma unroll 1
  for (int pass = 0; pass < 2; ++pass) {
    const int rbase = split * 256 + pass * 128;   // block's 128 b-rows

    // ---- (3a) stage f_i: coalesced float4 fp32 -> bf16 -> swizzled sA ----
    #pragma unroll
    for (int it = 0; it < 16; ++it) {
      int idx4 = it * 256 + t;               // 4096 float4: 128 rows x 32 c4
      int r = idx4 >> 5, c4 = idx4 & 31;
      const float4 v = *(const float4*)(feat + (size_t)(rbase + r) * FD +
                                        i * D_SZ + c4 * 4);
      ushort4 h;
      h.x = f2bf(v.x); h.y = f2bf(v.y); h.z = f2bf(v.z); h.w = f2bf(v.w);
      const int grp = c4 >> 1, half8 = (c4 & 1) * 8;
      *(ushort4*)((char*)sS + r * 256 + ((grp ^ (r & 7)) * 16 + half8)) = h;
    }
    __syncthreads();

    // ---- (3b) MFMA core (R1-verified): Y[b=32, e=128] per wave ----
    floatx4 acc[2][8];
    #pragma unroll
    for (int mf = 0; mf < 2; ++mf)
      #pragma unroll
      for (int nf = 0; nf < 8; ++nf)
        acc[mf][nf] = (floatx4){0.f, 0.f, 0.f, 0.f};

    const int row0 = w * 32 + l15;           // local rows of the a0/a1 frags
    #pragma unroll
    for (int k0 = 0; k0 < 4; ++k0) {
      const int kb = k0 * 64 + quad * 16;    // byte col base (8 bf16 = 16B)
      bf16x8 a0 = *(const bf16x8*)((const char*)sS + row0 * 256 +
                                   (kb ^ ((row0 & 7) << 4)));
      bf16x8 a1 = *(const bf16x8*)((const char*)sS + (row0 + 16) * 256 +
                                   (kb ^ ((row0 & 7) << 4)));
      #pragma unroll
      for (int nf = 0; nf < 8; ++nf) {
        const int e = nf * 16 + l15;
        bf16x8 bf = *(const bf16x8*)((const char*)sZT + e * 256 +
                                     (kb ^ ((e & 7) << 4)));
        acc[0][nf] = __builtin_amdgcn_mfma_f32_16x16x32_bf16(a0, bf, acc[0][nf], 0, 0, 0);
        acc[1][nf] = __builtin_amdgcn_mfma_f32_16x16x32_bf16(a1, bf, acc[1][nf], 0, 0, 0);
      }
    }

    // ---- (3c) epilogue: out[b] = sum_e Y[b,e] * f_j[b,e], fp32 f_j ----
    // C-layout: col(e) = nf*16 + l15, row(b) = quad*4 + reg. 16-lane groups
    // read 16 consecutive floats -> one 64B line per quad-group: coalesced.
    #pragma unroll
    for (int mf = 0; mf < 2; ++mf) {
      float pl[4] = {0.f, 0.f, 0.f, 0.f};
      const int rg = rbase + w * 32 + mf * 16 + quad * 4;  // global b of reg 0
      #pragma unroll
      for (int nf = 0; nf < 8; ++nf) {
        const int col = nf * 16 + l15;
        const float* fj = feat + (size_t)rg * FD + j * D_SZ + col;
        floatx4 c = acc[mf][nf];
        pl[0] += c[0] * fj[0];
        pl[1] += c[1] * fj[FD];
        pl[2] += c[2] * fj[2 * FD];
        pl[3] += c[3] * fj[3 * FD];
      }
      #pragma unroll
      for (int off = 1; off < 16; off <<= 1) {
        pl[0] += __shfl_xor(pl[0], off, 64);
        pl[1] += __shfl_xor(pl[1], off, 64);
        pl[2] += __shfl_xor(pl[2], off, 64);
        pl[3] += __shfl_xor(pl[3], off, 64);
      }
      if (l15 == 0) {
        size_t ob = (size_t)rg * (F_SZ * F_SZ) + (size_t)i * F_SZ + j;
        out[ob]                   = pl[0];
        out[ob + 1 * F_SZ * F_SZ] = pl[1];
        out[ob + 2 * F_SZ * F_SZ] = pl[2];
        out[ob + 3 * F_SZ * F_SZ] = pl[3];
      }
    }
    __syncthreads();   // protect sS before next pass's staging
  }
}

extern "C" void kernel_launch(void* const* d_in, const int* in_sizes, int n_in,
                              void* d_out, int out_size, void* d_ws, size_t ws_size,
                              hipStream_t stream) {
  const float* feat = (const float*)d_in[0];   // [B, F, D] fp32
  const float* mat  = (const float*)d_in[1];   // [F, F, D, D] fp32
  float* out = (float*)d_out;                  // [B, F, F] fp32

  // ONE dispatch: zeroing, Z transform, GEMM + epilogue all fused.
  interaction_fused_kernel<<<dim3(NPAIR * 4), dim3(256), 0, stream>>>(feat, mat, out);
}

// Round 8
// 146.449 us; speedup vs baseline: 1.7882x; 1.0427x over previous
//
#include <hip/hip_runtime.h>

#define B_SZ 1024
#define F_SZ 32
#define D_SZ 128
#define FD   4096               // floats per b-row of feature (fp32 input)
#define NPAIR 496               // F*(F-1)/2

typedef __bf16 bf16x8 __attribute__((ext_vector_type(8)));
typedef float floatx4 __attribute__((ext_vector_type(4)));
typedef unsigned short u16x8 __attribute__((ext_vector_type(8)));

__device__ __forceinline__ unsigned short f2bf(float f) {
  // round-to-nearest-even fp32 -> bf16 (no NaN inputs here)
  unsigned u = __float_as_uint(f);
  u += 0x7fffu + ((u >> 16) & 1u);
  return (unsigned short)(u >> 16);
}

__device__ __forceinline__ bf16x8 cvt8(float4 v0, float4 v1) {
  union { u16x8 u; bf16x8 b; } r;
  r.u[0] = f2bf(v0.x); r.u[1] = f2bf(v0.y); r.u[2] = f2bf(v0.z); r.u[3] = f2bf(v0.w);
  r.u[4] = f2bf(v1.x); r.u[5] = f2bf(v1.y); r.u[6] = f2bf(v1.z); r.u[7] = f2bf(v1.w);
  return r.b;
}

// ---------------- single fused kernel: 496 blocks = one per pair -----------
// Per block (4 waves): (1) zero disjoint lower-triangle slices of out,
// (2) Z ONCE per pair: coalesced fp32 read -> sigmoid/stretch/clip -> bf16 ->
//     in-LDS transpose -> XOR-swizzled sZT[e][d] (R7-verified, <=2-way banks),
// (3) 8 BARRIER-FREE passes x 128 b-rows (wave = 32 rows): A-frags loaded
//     directly from fp32 feat (2xfloat4 -> cvt8, no LDS staging, no barrier),
//     B-frags from resident sZT, R1-orientation MFMA (C: col=e, row=b),
//     coalesced fp32 f_j epilogue + 16-lane butterfly.
// All 496 blocks co-resident (2/CU cap); after the single Z barrier each
// wave streams independently -> TLP hides L2 latency instead of barriers
// exposing it. ONE dispatch: no prep kernel, no memset.
// __launch_bounds__(256,2): acc(64)+frags needs the 256-reg budget; (256,4)
// spilled in R4 (WRITE_SIZE 9->267MB). DO NOT raise the occupancy bound.
__global__ __launch_bounds__(256, 2)
void interaction_fused_kernel(const float* __restrict__ feat,
                              const float* __restrict__ mat,
                              float* __restrict__ out) {
  __shared__ unsigned short sZT[128 * 128];  // 32KB persistent: Z^T [e][d-swz]
  __shared__ unsigned short sS[128 * 128];   // 32KB scratch for the transpose

  const int t    = threadIdx.x;
  const int w    = t >> 6;
  const int lane = t & 63;
  const int l15  = lane & 15;
  const int quad = lane >> 4;

  const int bid = blockIdx.x;                // == pair id
  int p = bid, i = 0;
  while (p >= F_SZ - 1 - i) { p -= F_SZ - 1 - i; ++i; }
  const int j = i + 1 + p;

  // ---- (1) zero diag + lower triangle (disjoint from all pair writes) ----
  for (int bb = bid; bb < B_SZ; bb += NPAIR) {
    const int ii = t >> 3, s = t & 7;
    float* ob = out + (size_t)bb * (F_SZ * F_SZ) + ii * F_SZ;
    #pragma unroll
    for (int c = 0; c < 4; ++c) {
      int jj = s * 4 + c;
      if (jj <= ii) ob[jj] = 0.f;
    }
  }

  // ---- (2a) Z: coalesced fp32 read, gate transform, bf16, linear [d][e] ----
  {
    const float* zp = mat + (((size_t)i * F_SZ + j) * (size_t)(D_SZ * D_SZ));
    #pragma unroll
    for (int it = 0; it < 16; ++it) {
      int idx4 = it * 256 + t;               // 4096 float4 (e fastest)
      int d = idx4 >> 5, e4 = (idx4 & 31) * 4;
      const float4 v = *(const float4*)(zp + (size_t)d * D_SZ + e4);
      float zs[4] = {v.x, v.y, v.z, v.w};
      ushort4 h;
      unsigned short* hp = &h.x;
      #pragma unroll
      for (int c = 0; c < 4; ++c) {
        float s = 1.0f / (1.0f + __expf(-zs[c]));
        hp[c] = f2bf(fminf(1.0f, fmaxf(0.0f, fmaf(s, 1.2f, -0.1f))));
      }
      *(ushort4*)&sS[d * D_SZ + e4] = h;     // 8B writes, 2-way aliasing: free
    }
  }
  __syncthreads();

  // ---- (2b) transpose sS[d][e] -> sZT[e][d], 16B-group XOR swizzle ----
  {
    #pragma unroll
    for (int it = 0; it < 8; ++it) {
      int u = it * 256 + t;                  // 2048 units: e(128) x g(16)
      int e = u & 127, g = u >> 7;
      u16x8 pk;
      #pragma unroll
      for (int r = 0; r < 8; ++r) pk[r] = sS[(g * 8 + r) * D_SZ + e];
      *(u16x8*)&sZT[e * D_SZ + (g ^ (e & 7)) * 8] = pk;
    }
  }
  __syncthreads();   // the LAST barrier — pass loop below is barrier-free

  #pragma unroll 1
  for (int pass = 0; pass < 8; ++pass) {
    const int rbase = pass * 128 + w * 32;   // this wave's 32 b-rows

    // ---- (3a) A-frags straight from fp32 global (no staging, no barrier) --
    bf16x8 a0[4], a1[4];
    {
      const float* ap0 = feat + (size_t)(rbase + l15) * FD + i * D_SZ + quad * 8;
      const float* ap1 = ap0 + (size_t)16 * FD;
      #pragma unroll
      for (int k0 = 0; k0 < 4; ++k0) {
        a0[k0] = cvt8(*(const float4*)(ap0 + k0 * 32),
                      *(const float4*)(ap0 + k0 * 32 + 4));
        a1[k0] = cvt8(*(const float4*)(ap1 + k0 * 32),
                      *(const float4*)(ap1 + k0 * 32 + 4));
      }
    }

    // ---- (3b) MFMA core (R1-verified): Y[b=32, e=128] per wave ----
    floatx4 acc[2][8];
    #pragma unroll
    for (int mf = 0; mf < 2; ++mf)
      #pragma unroll
      for (int nf = 0; nf < 8; ++nf)
        acc[mf][nf] = (floatx4){0.f, 0.f, 0.f, 0.f};

    #pragma unroll
    for (int k0 = 0; k0 < 4; ++k0) {
      const int kb = k0 * 64 + quad * 16;    // byte col base (8 bf16 = 16B)
      #pragma unroll
      for (int nf = 0; nf < 8; ++nf) {
        const int e = nf * 16 + l15;
        bf16x8 bf = *(const bf16x8*)((const char*)sZT + e * 256 +
                                     (kb ^ ((e & 7) << 4)));
        acc[0][nf] = __builtin_amdgcn_mfma_f32_16x16x32_bf16(a0[k0], bf, acc[0][nf], 0, 0, 0);
        acc[1][nf] = __builtin_amdgcn_mfma_f32_16x16x32_bf16(a1[k0], bf, acc[1][nf], 0, 0, 0);
      }
    }

    // ---- (3c) epilogue: out[b] = sum_e Y[b,e] * f_j[b,e], fp32 f_j ----
    // C-layout: col(e) = nf*16 + l15, row(b) = quad*4 + reg. 16-lane groups
    // read 16 consecutive floats -> one 64B line per quad-group: coalesced.
    #pragma unroll
    for (int mf = 0; mf < 2; ++mf) {
      float pl[4] = {0.f, 0.f, 0.f, 0.f};
      const int rg = rbase + mf * 16 + quad * 4;   // global b-row of reg 0
      #pragma unroll
      for (int nf = 0; nf < 8; ++nf) {
        const int col = nf * 16 + l15;
        const float* fj = feat + (size_t)rg * FD + j * D_SZ + col;
        floatx4 c = acc[mf][nf];
        pl[0] += c[0] * fj[0];
        pl[1] += c[1] * fj[FD];
        pl[2] += c[2] * fj[2 * FD];
        pl[3] += c[3] * fj[3 * FD];
      }
      #pragma unroll
      for (int off = 1; off < 16; off <<= 1) {
        pl[0] += __shfl_xor(pl[0], off, 64);
        pl[1] += __shfl_xor(pl[1], off, 64);
        pl[2] += __shfl_xor(pl[2], off, 64);
        pl[3] += __shfl_xor(pl[3], off, 64);
      }
      if (l15 == 0) {
        size_t ob = (size_t)rg * (F_SZ * F_SZ) + (size_t)i * F_SZ + j;
        out[ob]                   = pl[0];
        out[ob + 1 * F_SZ * F_SZ] = pl[1];
        out[ob + 2 * F_SZ * F_SZ] = pl[2];
        out[ob + 3 * F_SZ * F_SZ] = pl[3];
      }
    }
  }
}

extern "C" void kernel_launch(void* const* d_in, const int* in_sizes, int n_in,
                              void* d_out, int out_size, void* d_ws, size_t ws_size,
                              hipStream_t stream) {
  const float* feat = (const float*)d_in[0];   // [B, F, D] fp32
  const float* mat  = (const float*)d_in[1];   // [F, F, D, D] fp32
  float* out = (float*)d_out;                  // [B, F, F] fp32

  // ONE dispatch: zeroing, Z transform, GEMM + epilogue all fused.
  interaction_fused_kernel<<<dim3(NPAIR), dim3(256), 0, stream>>>(feat, mat, out);
}